// Round 4
// baseline (829.001 us; speedup 1.0000x reference)
//
#include <hip/hip_runtime.h>

// ScaledDotProductAttention, MI355X. fp32 in/out.
// attn [2,16,2048,2048] fp32 (512 MiB) + out [2,16,2048,64] fp32, concat in d_out.
// Fast path (ws >= 24.3 MiB):
//   P0a: K -> Khi/Klo bf16 [2048][64] per head (RTNE hi + residual lo), in d_ws
//   P0b: V -> Vt fp16 [64][2048] per head (transposed), in d_ws
//   P1 : rowsum = sum_k exp(split-bf16 QK^T/8); rinv -> d_ws. No LDS, no barriers.
//   P2 : recompute split QK^T (B direct from ws), exp2, *rinv, nt-store attn,
//        fp16 P -> LDS, PV via fp16 MFMA (V direct from ws), store out.
// Fallback path: round-3 self-converting kernels (identical numerics).

#define S_LEN 2048
#define D_HEAD 64
#define QB 64
#define KB 128
#define NCHUNK (S_LEN / KB)     // 16
#define KPAD 72                  // fallback staging pad
#define PPAD 136                 // 128+8 fp16 -> 272B = 17*16B (odd) conflict-free
#define ATTN_ELEMS 134217728ull  // 2*16*2048*2048
#define LOG2E 1.44269504088896340736f

// ws layout (u16 elements)
#define WSE_KHI 0ull
#define WSE_KLO 4194304ull        // 32*2048*64
#define WSE_VT  8388608ull
#define WSE_RINV 12582912ull      // float[65536] lives here
#define WS_NEEDED_BYTES (12582912ull * 2ull + 65536ull * 4ull)  // 25427968

typedef short short8 __attribute__((ext_vector_type(8)));
typedef _Float16 half8 __attribute__((ext_vector_type(8)));
typedef float f32x16 __attribute__((ext_vector_type(16)));
typedef float floatx4 __attribute__((ext_vector_type(4)));
typedef unsigned short ushort8v __attribute__((ext_vector_type(8)));

#if __has_builtin(__builtin_amdgcn_exp2f)
#define EXP2F(x) __builtin_amdgcn_exp2f(x)
#else
#define EXP2F(x) exp2f(x)
#endif

static __device__ __forceinline__ unsigned short f2bf(float f) {
  unsigned u = __builtin_bit_cast(unsigned, f);
  u += 0x7fffu + ((u >> 16) & 1u);   // RTNE
  return (unsigned short)(u >> 16);
}
static __device__ __forceinline__ float bf2f(unsigned short h) {
  unsigned u = ((unsigned)h) << 16;
  return __builtin_bit_cast(float, u);
}
static __device__ __forceinline__ unsigned short f2h(float f) {
  return __builtin_bit_cast(unsigned short, (_Float16)f);
}

// ---------------- P0a: K -> Khi/Klo ----------------
__global__ __launch_bounds__(512) void k_prep_k(
    const float* __restrict__ kin, unsigned short* __restrict__ khi,
    unsigned short* __restrict__ klo) {
  const size_t base = ((size_t)blockIdx.x * 512 + threadIdx.x) * 8;  // 1024 blocks
  floatx4 a = *(const floatx4*)(kin + base);
  floatx4 b = *(const floatx4*)(kin + base + 4);
  ushort8v h, l;
#pragma unroll
  for (int j = 0; j < 4; ++j) {
    unsigned short ha = f2bf(a[j]); h[j] = ha; l[j] = f2bf(a[j] - bf2f(ha));
    unsigned short hb = f2bf(b[j]); h[4 + j] = hb; l[4 + j] = f2bf(b[j] - bf2f(hb));
  }
  *(ushort8v*)(khi + base) = h;
  *(ushort8v*)(klo + base) = l;
}

// ---------------- P0b: V -> Vt fp16 [64][2048] per head ----------------
__global__ __launch_bounds__(512) void k_prep_v(
    const float* __restrict__ vin, unsigned short* __restrict__ vt) {
  __shared__ __align__(16) unsigned short T[64 * KPAD];  // [d][kk] tile, pad 72
  const int tid = threadIdx.x;
  const int bh = blockIdx.x >> 3;       // 256 blocks = 32 heads x 8 parts
  const int part = blockIdx.x & 7;
  const float* V = vin + (size_t)bh * S_LEN * D_HEAD;
  unsigned short* Vt = vt + (size_t)bh * D_HEAD * S_LEN;

  const int kk_l = tid >> 3;            // 0..63
  const int d0 = (tid & 7) * 8;
  const int dd = tid >> 3;              // 0..63 (store role)
  const int kb = (tid & 7) * 8;

  for (int t = part * 4; t < part * 4 + 4; ++t) {
    const int kk0 = t * 64;
    floatx4 a = *(const floatx4*)(V + (size_t)(kk0 + kk_l) * D_HEAD + d0);
    floatx4 b = *(const floatx4*)(V + (size_t)(kk0 + kk_l) * D_HEAD + d0 + 4);
#pragma unroll
    for (int j = 0; j < 4; ++j) {
      T[(d0 + j) * KPAD + kk_l] = f2h(a[j]);
      T[(d0 + 4 + j) * KPAD + kk_l] = f2h(b[j]);
    }
    __syncthreads();
    *(ushort8v*)(Vt + (size_t)dd * S_LEN + kk0 + kb) = *(const ushort8v*)&T[dd * KPAD + kb];
    __syncthreads();
  }
}

// ---------------- P1: rowsum (fast) ----------------
__global__ __launch_bounds__(512, 4) void k_rowsum_f(
    const float* __restrict__ q, const unsigned short* __restrict__ khi,
    const unsigned short* __restrict__ klo, float* __restrict__ rinv) {
  __shared__ float rsum_s[QB];
  const int tid = threadIdx.x;
  const int lane = tid & 63;
  const int wid = tid >> 6;
  const int rg = wid & 1, cg = wid >> 1;
  const int bxs = (blockIdx.x & 7) * 128 + (blockIdx.x >> 3);  // XCD swizzle
  const int bh = bxs >> 5;
  const int qt = bxs & 31;

  const float* Q = q + (size_t)bh * S_LEN * D_HEAD;
  const unsigned short* KH = khi + (size_t)bh * S_LEN * D_HEAD;
  const unsigned short* KL = klo + (size_t)bh * S_LEN * D_HEAD;

  if (tid < QB) rsum_s[tid] = 0.0f;

  // A frags: row = lane&31, k = (lane>>5)*8 + j; pre-scaled 1/8, hi/lo split
  const int arow = qt * QB + rg * 32 + (lane & 31);
  const float* qp = Q + (size_t)arow * D_HEAD + ((lane >> 5) * 8);
  short8 ahi[4], alo[4];
#pragma unroll
  for (int ks = 0; ks < 4; ++ks) {
    floatx4 x0 = *(const floatx4*)(qp + ks * 16);
    floatx4 x1 = *(const floatx4*)(qp + ks * 16 + 4);
    ushort8v uh, ul;
#pragma unroll
    for (int j = 0; j < 4; ++j) {
      float xa = x0[j] * 0.125f; unsigned short ha = f2bf(xa);
      uh[j] = ha; ul[j] = f2bf(xa - bf2f(ha));
      float xb = x1[j] * 0.125f; unsigned short hb = f2bf(xb);
      uh[4 + j] = hb; ul[4 + j] = f2bf(xb - bf2f(hb));
    }
    ahi[ks] = __builtin_bit_cast(short8, uh);
    alo[ks] = __builtin_bit_cast(short8, ul);
  }

  float psum[16];
#pragma unroll
  for (int i = 0; i < 16; ++i) psum[i] = 0.0f;

  const size_t brow0 = (size_t)(cg * 32 + (lane & 31)) * D_HEAD + (lane >> 5) * 8;

  for (int ch = 0; ch < NCHUNK; ++ch) {
    const size_t cbase = (size_t)ch * KB * D_HEAD + brow0;
    f32x16 acc = {};
#pragma unroll
    for (int ks = 0; ks < 4; ++ks) {
      ushort8v bhu = *(const ushort8v*)(KH + cbase + ks * 16);
      ushort8v blu = *(const ushort8v*)(KL + cbase + ks * 16);
      short8 bh8 = __builtin_bit_cast(short8, bhu);
      short8 bl8 = __builtin_bit_cast(short8, blu);
      acc = __builtin_amdgcn_mfma_f32_32x32x16_bf16(alo[ks], bh8, acc, 0, 0, 0);
      acc = __builtin_amdgcn_mfma_f32_32x32x16_bf16(ahi[ks], bl8, acc, 0, 0, 0);
      acc = __builtin_amdgcn_mfma_f32_32x32x16_bf16(ahi[ks], bh8, acc, 0, 0, 0);
    }
#pragma unroll
    for (int i = 0; i < 16; ++i) psum[i] += EXP2F(acc[i] * LOG2E);
  }

#pragma unroll
  for (int off = 1; off < 32; off <<= 1) {
#pragma unroll
    for (int i = 0; i < 16; ++i) psum[i] += __shfl_xor(psum[i], off, 64);
  }
  if ((lane & 31) == 0) {
    const int rbase = rg * 32 + 4 * (lane >> 5);
#pragma unroll
    for (int i = 0; i < 16; ++i)
      atomicAdd(&rsum_s[rbase + (i & 3) + 8 * (i >> 2)], psum[i]);
  }
  __syncthreads();
  if (tid < QB)
    rinv[(size_t)bh * S_LEN + qt * QB + tid] = 1.0f / rsum_s[tid];
}

// ---------------- P2: attn + out (fast) ----------------
__global__ __launch_bounds__(512, 4) void k_attn_f(
    const float* __restrict__ q, const unsigned short* __restrict__ khi,
    const unsigned short* __restrict__ klo, const unsigned short* __restrict__ vt,
    const float* __restrict__ rinv, float* __restrict__ outbuf) {
  __shared__ __align__(16) unsigned short Pst[QB * PPAD];  // 17408 B (also red buf)
  __shared__ float rinv_s[QB];

  const int tid = threadIdx.x;
  const int lane = tid & 63;
  const int wid = tid >> 6;
  const int rg = wid & 1, cg = wid >> 1;           // QK roles
  const int dg = (wid >> 1) & 1, kh = wid >> 2;    // PV roles
  const int bxs = (blockIdx.x & 7) * 128 + (blockIdx.x >> 3);  // XCD swizzle
  const int bh = bxs >> 5;
  const int qt = bxs & 31;

  const float* Q = q + (size_t)bh * S_LEN * D_HEAD;
  const unsigned short* KH = khi + (size_t)bh * S_LEN * D_HEAD;
  const unsigned short* KL = klo + (size_t)bh * S_LEN * D_HEAD;
  const unsigned short* VT = vt + (size_t)bh * D_HEAD * S_LEN;
  float* attn_base = outbuf + (size_t)bh * S_LEN * S_LEN + (size_t)qt * QB * S_LEN;
  float* out_base = outbuf + ATTN_ELEMS + (size_t)bh * S_LEN * D_HEAD +
                    (size_t)qt * QB * D_HEAD;

  if (tid < QB) rinv_s[tid] = rinv[(size_t)bh * S_LEN + qt * QB + tid];

  const int arow = qt * QB + rg * 32 + (lane & 31);
  const float* qp = Q + (size_t)arow * D_HEAD + ((lane >> 5) * 8);
  short8 ahi[4], alo[4];
#pragma unroll
  for (int ks = 0; ks < 4; ++ks) {
    floatx4 x0 = *(const floatx4*)(qp + ks * 16);
    floatx4 x1 = *(const floatx4*)(qp + ks * 16 + 4);
    ushort8v uh, ul;
#pragma unroll
    for (int j = 0; j < 4; ++j) {
      float xa = x0[j] * 0.125f; unsigned short ha = f2bf(xa);
      uh[j] = ha; ul[j] = f2bf(xa - bf2f(ha));
      float xb = x1[j] * 0.125f; unsigned short hb = f2bf(xb);
      uh[4 + j] = hb; ul[4 + j] = f2bf(xb - bf2f(hb));
    }
    ahi[ks] = __builtin_bit_cast(short8, uh);
    alo[ks] = __builtin_bit_cast(short8, ul);
  }
  __syncthreads();

  floatx4 rvec[4];
  {
    const int rb = rg * 32 + 4 * (lane >> 5);
#pragma unroll
    for (int m = 0; m < 4; ++m) rvec[m] = *(const floatx4*)&rinv_s[rb + 8 * m];
  }

  f32x16 oacc = {};
  const size_t brow0 = (size_t)(cg * 32 + (lane & 31)) * D_HEAD + (lane >> 5) * 8;
  const int boff = (lane >> 5) * 8;

  for (int ch = 0; ch < NCHUNK; ++ch) {
    const int kk0 = ch * KB;
    // QK^T, B direct from ws (L2-resident)
    f32x16 acc = {};
    const size_t cbase = (size_t)kk0 * D_HEAD + brow0;
#pragma unroll
    for (int ks = 0; ks < 4; ++ks) {
      ushort8v bhu = *(const ushort8v*)(KH + cbase + ks * 16);
      ushort8v blu = *(const ushort8v*)(KL + cbase + ks * 16);
      short8 bh8 = __builtin_bit_cast(short8, bhu);
      short8 bl8 = __builtin_bit_cast(short8, blu);
      acc = __builtin_amdgcn_mfma_f32_32x32x16_bf16(alo[ks], bh8, acc, 0, 0, 0);
      acc = __builtin_amdgcn_mfma_f32_32x32x16_bf16(ahi[ks], bl8, acc, 0, 0, 0);
      acc = __builtin_amdgcn_mfma_f32_32x32x16_bf16(ahi[ks], bh8, acc, 0, 0, 0);
    }
    // exp -> normalize -> attn nt-store + fp16 stash
    {
      const int rbase = rg * 32 + 4 * (lane >> 5);
      const int colg = kk0 + cg * 32 + (lane & 31);
#pragma unroll
      for (int i = 0; i < 16; ++i) {
        float p = EXP2F(acc[i] * LOG2E);
        float at = p * rvec[i >> 2][i & 3];
        const int rl = rbase + (i & 3) + 8 * (i >> 2);
        __builtin_nontemporal_store(at, &attn_base[(size_t)rl * S_LEN + colg]);
        Pst[rl * PPAD + cg * 32 + (lane & 31)] = f2h(at);
      }
    }
    __syncthreads();
    // PV: P from LDS, V direct from ws
#pragma unroll
    for (int ks = 0; ks < 4; ++ks) {
      const int kofs = kh * 64 + ks * 16 + boff;
      ushort8v pu = *(const ushort8v*)&Pst[(rg * 32 + (lane & 31)) * PPAD + kofs];
      ushort8v vu = *(const ushort8v*)(VT + (size_t)(dg * 32 + (lane & 31)) * S_LEN + kk0 + kofs);
      oacc = __builtin_amdgcn_mfma_f32_32x32x16_f16(
          __builtin_bit_cast(half8, pu), __builtin_bit_cast(half8, vu), oacc, 0, 0, 0);
    }
    __syncthreads();
  }

  // combine kk-halves via LDS (alias Pst: 16 KiB needed, 17 KiB there)
  float* red = (float*)Pst;
  const int t4 = wid & 3;
  if (kh == 1) {
#pragma unroll
    for (int i = 0; i < 16; ++i) red[t4 * 1024 + i * 64 + lane] = oacc[i];
  }
  __syncthreads();
  if (kh == 0) {
#pragma unroll
    for (int i = 0; i < 16; ++i) oacc[i] += red[t4 * 1024 + i * 64 + lane];
    const int rbase = rg * 32 + 4 * (lane >> 5);
#pragma unroll
    for (int i = 0; i < 16; ++i) {
      const int rl = rbase + (i & 3) + 8 * (i >> 2);
      out_base[(size_t)rl * D_HEAD + dg * 32 + (lane & 31)] = oacc[i];
    }
  }
}

// ================= fallback (round-3) kernels =================
__global__ __launch_bounds__(512, 4) void k_rowsum(
    const float* __restrict__ q, const float* __restrict__ k,
    float* __restrict__ outbuf) {
  __shared__ __align__(16) unsigned short KhiS[KB * KPAD];
  __shared__ __align__(16) unsigned short KloS[KB * KPAD];
  __shared__ float rsum_s[QB];
  const int tid = threadIdx.x;
  const int lane = tid & 63;
  const int wid = tid >> 6;
  const int rg = wid & 1, cg = wid >> 1;
  const int bh = blockIdx.x >> 5;
  const int qt = blockIdx.x & 31;
  const float* Q = q + (size_t)bh * S_LEN * D_HEAD;
  const float* K = k + (size_t)bh * S_LEN * D_HEAD;
  float* rinv_out = outbuf + ATTN_ELEMS + (size_t)bh * S_LEN * D_HEAD +
                    (size_t)qt * QB * D_HEAD;
  if (tid < QB) rsum_s[tid] = 0.0f;
  const int arow = qt * QB + rg * 32 + (lane & 31);
  const float* qp = Q + (size_t)arow * D_HEAD + ((lane >> 5) * 8);
  short8 ahi[4], alo[4];
#pragma unroll
  for (int ks = 0; ks < 4; ++ks) {
    floatx4 x0 = *(const floatx4*)(qp + ks * 16);
    floatx4 x1 = *(const floatx4*)(qp + ks * 16 + 4);
    ushort8v uh, ul;
#pragma unroll
    for (int j = 0; j < 4; ++j) {
      float xa = x0[j] * 0.125f; unsigned short ha = f2bf(xa);
      uh[j] = ha; ul[j] = f2bf(xa - bf2f(ha));
      float xb = x1[j] * 0.125f; unsigned short hb = f2bf(xb);
      uh[4 + j] = hb; ul[4 + j] = f2bf(xb - bf2f(hb));
    }
    ahi[ks] = __builtin_bit_cast(short8, uh);
    alo[ks] = __builtin_bit_cast(short8, ul);
  }
  float psum[16];
#pragma unroll
  for (int i = 0; i < 16; ++i) psum[i] = 0.0f;
  const int srow = tid >> 2;
  const int scol = (tid & 3) * 16;
  const int bcol = cg * 32 + (lane & 31);
  const int boff = (lane >> 5) * 8;
  for (int ch = 0; ch < NCHUNK; ++ch) {
    const int kk0 = ch * KB;
    {
      const float* src = K + (size_t)(kk0 + srow) * D_HEAD + scol;
      floatx4 v0 = *(const floatx4*)(src);
      floatx4 v1 = *(const floatx4*)(src + 4);
      floatx4 v2 = *(const floatx4*)(src + 8);
      floatx4 v3 = *(const floatx4*)(src + 12);
      ushort8v h0, h1, l0, l1;
#pragma unroll
      for (int j = 0; j < 4; ++j) {
        unsigned short a0 = f2bf(v0[j]); h0[j] = a0; l0[j] = f2bf(v0[j] - bf2f(a0));
        unsigned short a1 = f2bf(v1[j]); h0[4+j] = a1; l0[4+j] = f2bf(v1[j] - bf2f(a1));
        unsigned short a2 = f2bf(v2[j]); h1[j] = a2; l1[j] = f2bf(v2[j] - bf2f(a2));
        unsigned short a3 = f2bf(v3[j]); h1[4+j] = a3; l1[4+j] = f2bf(v3[j] - bf2f(a3));
      }
      *(ushort8v*)&KhiS[srow * KPAD + scol] = h0;
      *(ushort8v*)&KhiS[srow * KPAD + scol + 8] = h1;
      *(ushort8v*)&KloS[srow * KPAD + scol] = l0;
      *(ushort8v*)&KloS[srow * KPAD + scol + 8] = l1;
    }
    __syncthreads();
    f32x16 acc = {};
#pragma unroll
    for (int ks = 0; ks < 4; ++ks) {
      ushort8v bhu = *(const ushort8v*)&KhiS[bcol * KPAD + ks * 16 + boff];
      ushort8v blu = *(const ushort8v*)&KloS[bcol * KPAD + ks * 16 + boff];
      short8 bh8 = __builtin_bit_cast(short8, bhu);
      short8 bl8 = __builtin_bit_cast(short8, blu);
      acc = __builtin_amdgcn_mfma_f32_32x32x16_bf16(alo[ks], bh8, acc, 0, 0, 0);
      acc = __builtin_amdgcn_mfma_f32_32x32x16_bf16(ahi[ks], bl8, acc, 0, 0, 0);
      acc = __builtin_amdgcn_mfma_f32_32x32x16_bf16(ahi[ks], bh8, acc, 0, 0, 0);
    }
#pragma unroll
    for (int i = 0; i < 16; ++i) psum[i] += EXP2F(acc[i] * LOG2E);
    __syncthreads();
  }
#pragma unroll
  for (int off = 1; off < 32; off <<= 1) {
#pragma unroll
    for (int i = 0; i < 16; ++i) psum[i] += __shfl_xor(psum[i], off, 64);
  }
  if ((lane & 31) == 0) {
    const int rbase = rg * 32 + 4 * (lane >> 5);
#pragma unroll
    for (int i = 0; i < 16; ++i)
      atomicAdd(&rsum_s[rbase + (i & 3) + 8 * (i >> 2)], psum[i]);
  }
  __syncthreads();
  if (tid < QB) rinv_out[tid] = 1.0f / rsum_s[tid];
}

__global__ __launch_bounds__(512, 4) void k_attn(
    const float* __restrict__ q, const float* __restrict__ k,
    const float* __restrict__ v, float* __restrict__ outbuf) {
  __shared__ __align__(16) unsigned short KhiS[KB * KPAD];
  __shared__ __align__(16) unsigned short KloS[KB * KPAD];
  __shared__ __align__(16) unsigned short Pst[QB * PPAD];
  __shared__ __align__(16) unsigned short VtS[D_HEAD * PPAD];
  __shared__ float rinv_s[QB];
  const int tid = threadIdx.x;
  const int lane = tid & 63;
  const int wid = tid >> 6;
  const int rg = wid & 1, cg = wid >> 1;
  const int dg = (wid >> 1) & 1, kh = wid >> 2;
  const int bh = blockIdx.x >> 5;
  const int qt = blockIdx.x & 31;
  const float* Q = q + (size_t)bh * S_LEN * D_HEAD;
  const float* K = k + (size_t)bh * S_LEN * D_HEAD;
  const float* V = v + (size_t)bh * S_LEN * D_HEAD;
  float* attn_base = outbuf + (size_t)bh * S_LEN * S_LEN + (size_t)qt * QB * S_LEN;
  float* out_base = outbuf + ATTN_ELEMS + (size_t)bh * S_LEN * D_HEAD +
                    (size_t)qt * QB * D_HEAD;
  if (tid < QB) rinv_s[tid] = out_base[tid];
  const int arow = qt * QB + rg * 32 + (lane & 31);
  const float* qp = Q + (size_t)arow * D_HEAD + ((lane >> 5) * 8);
  short8 ahi[4], alo[4];
#pragma unroll
  for (int ks = 0; ks < 4; ++ks) {
    floatx4 x0 = *(const floatx4*)(qp + ks * 16);
    floatx4 x1 = *(const floatx4*)(qp + ks * 16 + 4);
    ushort8v uh, ul;
#pragma unroll
    for (int j = 0; j < 4; ++j) {
      float xa = x0[j] * 0.125f; unsigned short ha = f2bf(xa);
      uh[j] = ha; ul[j] = f2bf(xa - bf2f(ha));
      float xb = x1[j] * 0.125f; unsigned short hb = f2bf(xb);
      uh[4 + j] = hb; ul[4 + j] = f2bf(xb - bf2f(hb));
    }
    ahi[ks] = __builtin_bit_cast(short8, uh);
    alo[ks] = __builtin_bit_cast(short8, ul);
  }
  __syncthreads();
  floatx4 rvec[4];
  {
    const int rb = rg * 32 + 4 * (lane >> 5);
#pragma unroll
    for (int m = 0; m < 4; ++m) rvec[m] = *(const floatx4*)&rinv_s[rb + 8 * m];
  }
  f32x16 oacc = {};
  const int srow = tid >> 2;
  const int scol = (tid & 3) * 16;
  const int bcol = cg * 32 + (lane & 31);
  const int boff = (lane >> 5) * 8;
  for (int ch = 0; ch < NCHUNK; ++ch) {
    const int kk0 = ch * KB;
    {
      const float* src = K + (size_t)(kk0 + srow) * D_HEAD + scol;
      floatx4 v0 = *(const floatx4*)(src);
      floatx4 v1 = *(const floatx4*)(src + 4);
      floatx4 v2 = *(const floatx4*)(src + 8);
      floatx4 v3 = *(const floatx4*)(src + 12);
      ushort8v h0, h1, l0, l1;
#pragma unroll
      for (int j = 0; j < 4; ++j) {
        unsigned short a0 = f2bf(v0[j]); h0[j] = a0; l0[j] = f2bf(v0[j] - bf2f(a0));
        unsigned short a1 = f2bf(v1[j]); h0[4+j] = a1; l0[4+j] = f2bf(v1[j] - bf2f(a1));
        unsigned short a2 = f2bf(v2[j]); h1[j] = a2; l1[j] = f2bf(v2[j] - bf2f(a2));
        unsigned short a3 = f2bf(v3[j]); h1[4+j] = a3; l1[4+j] = f2bf(v3[j] - bf2f(a3));
      }
      *(ushort8v*)&KhiS[srow * KPAD + scol] = h0;
      *(ushort8v*)&KhiS[srow * KPAD + scol + 8] = h1;
      *(ushort8v*)&KloS[srow * KPAD + scol] = l0;
      *(ushort8v*)&KloS[srow * KPAD + scol + 8] = l1;
    }
    {
#pragma unroll
      for (int half = 0; half < 2; ++half) {
        const float* vsrc = V + (size_t)(kk0 + half * 64 + wid * 8) * D_HEAD + lane;
        ushort8v hv;
#pragma unroll
        for (int i = 0; i < 8; ++i) hv[i] = f2h(vsrc[(size_t)i * D_HEAD]);
        *(ushort8v*)&VtS[lane * PPAD + half * 64 + wid * 8] = hv;
      }
    }
    __syncthreads();
    f32x16 acc = {};
#pragma unroll
    for (int ks = 0; ks < 4; ++ks) {
      ushort8v bhu = *(const ushort8v*)&KhiS[bcol * KPAD + ks * 16 + boff];
      ushort8v blu = *(const ushort8v*)&KloS[bcol * KPAD + ks * 16 + boff];
      short8 bh8 = __builtin_bit_cast(short8, bhu);
      short8 bl8 = __builtin_bit_cast(short8, blu);
      acc = __builtin_amdgcn_mfma_f32_32x32x16_bf16(alo[ks], bh8, acc, 0, 0, 0);
      acc = __builtin_amdgcn_mfma_f32_32x32x16_bf16(ahi[ks], bl8, acc, 0, 0, 0);
      acc = __builtin_amdgcn_mfma_f32_32x32x16_bf16(ahi[ks], bh8, acc, 0, 0, 0);
    }
    {
      const int rbase = rg * 32 + 4 * (lane >> 5);
      const int colg = kk0 + cg * 32 + (lane & 31);
#pragma unroll
      for (int i = 0; i < 16; ++i) {
        float p = EXP2F(acc[i] * LOG2E);
        float at = p * rvec[i >> 2][i & 3];
        const int rl = rbase + (i & 3) + 8 * (i >> 2);
        __builtin_nontemporal_store(at, &attn_base[(size_t)rl * S_LEN + colg]);
        Pst[rl * PPAD + cg * 32 + (lane & 31)] = f2h(at);
      }
    }
    __syncthreads();
#pragma unroll
    for (int ks = 0; ks < 4; ++ks) {
      const int kofs = kh * 64 + ks * 16 + boff;
      ushort8v pu = *(const ushort8v*)&Pst[(rg * 32 + (lane & 31)) * PPAD + kofs];
      ushort8v vu = *(const ushort8v*)&VtS[(dg * 32 + (lane & 31)) * PPAD + kofs];
      oacc = __builtin_amdgcn_mfma_f32_32x32x16_f16(
          __builtin_bit_cast(half8, pu), __builtin_bit_cast(half8, vu), oacc, 0, 0, 0);
    }
    __syncthreads();
  }
  float* red = (float*)KhiS;
  const int t4 = wid & 3;
  if (kh == 1) {
#pragma unroll
    for (int i = 0; i < 16; ++i) red[t4 * 1024 + i * 64 + lane] = oacc[i];
  }
  __syncthreads();
  if (kh == 0) {
#pragma unroll
    for (int i = 0; i < 16; ++i) oacc[i] += red[t4 * 1024 + i * 64 + lane];
    const int rbase = rg * 32 + 4 * (lane >> 5);
#pragma unroll
    for (int i = 0; i < 16; ++i) {
      const int rl = rbase + (i & 3) + 8 * (i >> 2);
      out_base[(size_t)rl * D_HEAD + dg * 32 + (lane & 31)] = oacc[i];
    }
  }
}

extern "C" void kernel_launch(void* const* d_in, const int* in_sizes, int n_in,
                              void* d_out, int out_size, void* d_ws, size_t ws_size,
                              hipStream_t stream) {
  const float* q = (const float*)d_in[0];
  const float* k = (const float*)d_in[1];
  const float* v = (const float*)d_in[2];
  float* out = (float*)d_out;
  (void)in_sizes; (void)n_in; (void)out_size;

  dim3 blk(512);
  if (ws_size >= WS_NEEDED_BYTES) {
    unsigned short* wsu = (unsigned short*)d_ws;
    unsigned short* khi = wsu + WSE_KHI;
    unsigned short* klo = wsu + WSE_KLO;
    unsigned short* vt = wsu + WSE_VT;
    float* rinv = (float*)(wsu + WSE_RINV);
    hipLaunchKernelGGL(k_prep_k, dim3(1024), blk, 0, stream, k, khi, klo);
    hipLaunchKernelGGL(k_prep_v, dim3(256), blk, 0, stream, v, vt);
    hipLaunchKernelGGL(k_rowsum_f, dim3(1024), blk, 0, stream, q, khi, klo, rinv);
    hipLaunchKernelGGL(k_attn_f, dim3(1024), blk, 0, stream, q, khi, klo, vt, rinv, out);
  } else {
    hipLaunchKernelGGL(k_rowsum, dim3(1024), blk, 0, stream, q, k, out);
    hipLaunchKernelGGL(k_attn, dim3(1024), blk, 0, stream, q, k, v, out);
  }
}

// Round 5
// 708.239 us; speedup vs baseline: 1.1705x; 1.1705x over previous
//
#include <hip/hip_runtime.h>

// ScaledDotProductAttention, MI355X. fp32 in/out.
// attn [2,16,2048,2048] fp32 (512 MiB) + out [2,16,2048,64] fp32, concat in d_out.
// Fast path (ws >= 24 MiB):
//   P0: K -> Khi/Klo bf16 + V -> Vt fp16, all stored PRE-PERMUTED into MFMA
//       B-fragment order, so hot-loop operand loads are lane-contiguous:
//       K frag: [ch][cg][ks][lane][8]  (frag[.]=K[ch*128+cg*32+(l&31)][ks*16+(l>>5)*8+j])
//       V frag: [ch][kh][dg][ks][lane][8] (=V[ch*128+kh*64+ks*16+(l>>5)*8+j][dg*32+(l&31)])
//   P1 (fused): pass1 rowsum (no LDS, no barriers) -> 1/rowsum in LDS ->
//       pass2 recompute split QK^T, exp2, *rinv, nt-store attn, fp16 P via
//       double-buffered LDS (1 barrier/chunk), fp16 MFMA PV, store out.
// Fallback path: round-3 self-converting kernels (identical numerics).

#define S_LEN 2048
#define D_HEAD 64
#define QB 64
#define KB 128
#define NCHUNK (S_LEN / KB)     // 16
#define KPAD 72                  // fallback staging pad
#define PPAD 136                 // 128+8 fp16 -> 272B = 17*16B (odd) conflict-free
#define ATTN_ELEMS 134217728ull  // 2*16*2048*2048
#define LOG2E 1.44269504088896340736f
#define HFRAG 131072ull          // halves per head per tensor (2048*64)

// ws layout (u16 elements): KHI | KLO | VT
#define WSE_KHI 0ull
#define WSE_KLO 4194304ull       // 32*HFRAG
#define WSE_VT  8388608ull
#define WS_NEEDED_BYTES (12582912ull * 2ull)  // 24 MiB

typedef short short8 __attribute__((ext_vector_type(8)));
typedef _Float16 half8 __attribute__((ext_vector_type(8)));
typedef float f32x16 __attribute__((ext_vector_type(16)));
typedef float floatx4 __attribute__((ext_vector_type(4)));
typedef unsigned short ushort8v __attribute__((ext_vector_type(8)));

#if __has_builtin(__builtin_amdgcn_exp2f)
#define EXP2F(x) __builtin_amdgcn_exp2f(x)
#else
#define EXP2F(x) exp2f(x)
#endif

static __device__ __forceinline__ unsigned short f2bf(float f) {
  unsigned u = __builtin_bit_cast(unsigned, f);
  u += 0x7fffu + ((u >> 16) & 1u);   // RTNE
  return (unsigned short)(u >> 16);
}
static __device__ __forceinline__ float bf2f(unsigned short h) {
  unsigned u = ((unsigned)h) << 16;
  return __builtin_bit_cast(float, u);
}
static __device__ __forceinline__ unsigned short f2h(float f) {
  return __builtin_bit_cast(unsigned short, (_Float16)f);
}

// ---------------- P0: prep K (blocks 0..511) and V (blocks 512..1023) ----------------
__global__ __launch_bounds__(512) void k_prep(
    const float* __restrict__ kin, const float* __restrict__ vin,
    unsigned short* __restrict__ khi, unsigned short* __restrict__ klo,
    unsigned short* __restrict__ vt) {
  __shared__ __align__(16) unsigned short T[64 * PPAD];
  const int tid = threadIdx.x;
  const int b = blockIdx.x;
  if (b < 512) {  // ---- K path: b = bh*16 + ch
    const int bh = b >> 4, ch = b & 15;
    const int srow = tid >> 2;          // 0..127 (K row within chunk)
    const int ks = tid & 3;
    const int d0 = ks * 16;
    const float* src = kin + ((size_t)bh * S_LEN + ch * KB + srow) * D_HEAD + d0;
    floatx4 v0 = *(const floatx4*)(src);
    floatx4 v1 = *(const floatx4*)(src + 4);
    floatx4 v2 = *(const floatx4*)(src + 8);
    floatx4 v3 = *(const floatx4*)(src + 12);
    ushort8v h0, h1, l0, l1;
#pragma unroll
    for (int j = 0; j < 4; ++j) {
      unsigned short a0 = f2bf(v0[j]); h0[j] = a0; l0[j] = f2bf(v0[j] - bf2f(a0));
      unsigned short a1 = f2bf(v1[j]); h0[4+j] = a1; l0[4+j] = f2bf(v1[j] - bf2f(a1));
      unsigned short a2 = f2bf(v2[j]); h1[j] = a2; l1[j] = f2bf(v2[j] - bf2f(a2));
      unsigned short a3 = f2bf(v3[j]); h1[4+j] = a3; l1[4+j] = f2bf(v3[j] - bf2f(a3));
    }
    const int cg = srow >> 5, r = srow & 31;
    // frag base for (ch,cg,ks): ((ch*4+cg)*4+ks)*64 lanes * 8 halves
    const size_t base = (size_t)bh * HFRAG +
                        ((size_t)(ch * 4 + cg) * 2048 + (size_t)ks * 512);
    *(ushort8v*)(khi + base + r * 8) = h0;          // lanes 0..31 (hi=0): d j=0..7
    *(ushort8v*)(khi + base + (32 + r) * 8) = h1;   // lanes 32..63 (hi=1): d j=8..15
    *(ushort8v*)(klo + base + r * 8) = l0;
    *(ushort8v*)(klo + base + (32 + r) * 8) = l1;
  } else {        // ---- V path: transpose via LDS, emit permuted fp16 frags
    const int bb = b - 512;
    const int bh = bb >> 4, ch = bb & 15;
    const int srow = tid >> 2;          // 0..127 (V row = kk within chunk)
    const int d0 = (tid & 3) * 16;
    const float* src = vin + ((size_t)bh * S_LEN + ch * KB + srow) * D_HEAD + d0;
    floatx4 v0 = *(const floatx4*)(src);
    floatx4 v1 = *(const floatx4*)(src + 4);
    floatx4 v2 = *(const floatx4*)(src + 8);
    floatx4 v3 = *(const floatx4*)(src + 12);
#pragma unroll
    for (int j = 0; j < 4; ++j) {
      T[(d0 + j) * PPAD + srow] = f2h(v0[j]);
      T[(d0 + 4 + j) * PPAD + srow] = f2h(v1[j]);
      T[(d0 + 8 + j) * PPAD + srow] = f2h(v2[j]);
      T[(d0 + 12 + j) * PPAD + srow] = f2h(v3[j]);
    }
    __syncthreads();
    const size_t obase = (size_t)bh * HFRAG + (size_t)ch * 8192;
#pragma unroll
    for (int pp = 0; pp < 2; ++pp) {
      const int p = tid * 2 + pp;       // p = ((kh*2+dg)*4+ks)*64 + lane
      const int pl = p & 63;
      const int ks2 = (p >> 6) & 3;
      const int dg2 = (p >> 8) & 1;
      const int kh2 = (p >> 9) & 1;
      const int rowd = dg2 * 32 + (pl & 31);
      const int kkl = kh2 * 64 + ks2 * 16 + (pl >> 5) * 8;
      *(ushort8v*)(vt + obase + (size_t)p * 8) = *(const ushort8v*)&T[rowd * PPAD + kkl];
    }
  }
}

// ---------------- P1: fused rowsum + attn + out ----------------
__global__ __launch_bounds__(512, 4) void k_fused(
    const float* __restrict__ q, const unsigned short* __restrict__ khi,
    const unsigned short* __restrict__ klo, const unsigned short* __restrict__ vt,
    float* __restrict__ outbuf) {
  __shared__ __align__(16) unsigned short Pst[2][QB * PPAD];  // double-buffered
  __shared__ float rsum_s[QB];

  const int tid = threadIdx.x;
  const int lane = tid & 63;
  const int wid = tid >> 6;
  const int rg = wid & 1, cg = wid >> 1;           // QK roles
  const int dg = (wid >> 1) & 1, kh = wid >> 2;    // PV roles
  const int bxs = (blockIdx.x & 7) * 128 + (blockIdx.x >> 3);  // XCD swizzle
  const int bh = bxs >> 5;
  const int qt = bxs & 31;

  const float* Q = q + (size_t)bh * S_LEN * D_HEAD;
  const unsigned short* KHb = khi + (size_t)bh * HFRAG;
  const unsigned short* KLb = klo + (size_t)bh * HFRAG;
  const unsigned short* VTb = vt + (size_t)bh * HFRAG;
  float* attn_base = outbuf + (size_t)bh * S_LEN * S_LEN + (size_t)qt * QB * S_LEN;
  float* out_base = outbuf + ATTN_ELEMS + ((size_t)bh * S_LEN + qt * QB) * D_HEAD;

  if (tid < QB) rsum_s[tid] = 0.0f;

  // Q A-frags, hi/lo split, pre-scaled 1/8. A: row=lane&31, k=(lane>>5)*8+j
  const int arow = qt * QB + rg * 32 + (lane & 31);
  const float* qp = Q + (size_t)arow * D_HEAD + ((lane >> 5) * 8);
  short8 ahi[4], alo[4];
#pragma unroll
  for (int ks = 0; ks < 4; ++ks) {
    floatx4 x0 = *(const floatx4*)(qp + ks * 16);
    floatx4 x1 = *(const floatx4*)(qp + ks * 16 + 4);
    ushort8v uh, ul;
#pragma unroll
    for (int j = 0; j < 4; ++j) {
      float xa = x0[j] * 0.125f; unsigned short ha = f2bf(xa);
      uh[j] = ha; ul[j] = f2bf(xa - bf2f(ha));
      float xb = x1[j] * 0.125f; unsigned short hb = f2bf(xb);
      uh[4 + j] = hb; ul[4 + j] = f2bf(xb - bf2f(hb));
    }
    ahi[ks] = __builtin_bit_cast(short8, uh);
    alo[ks] = __builtin_bit_cast(short8, ul);
  }
  __syncthreads();  // rsum_s init visible before pass-1 atomics

  // ---------- pass 1: rowsum (no barriers, coalesced frag loads) ----------
  float psum[16];
#pragma unroll
  for (int i = 0; i < 16; ++i) psum[i] = 0.0f;

  for (int ch = 0; ch < NCHUNK; ++ch) {
    const size_t off = (size_t)(ch * 4 + cg) * 2048 + (size_t)lane * 8;
    f32x16 acc = {};
#pragma unroll
    for (int ks = 0; ks < 4; ++ks) {
      short8 bh8 = __builtin_bit_cast(short8, *(const ushort8v*)(KHb + off + ks * 512));
      short8 bl8 = __builtin_bit_cast(short8, *(const ushort8v*)(KLb + off + ks * 512));
      acc = __builtin_amdgcn_mfma_f32_32x32x16_bf16(alo[ks], bh8, acc, 0, 0, 0);
      acc = __builtin_amdgcn_mfma_f32_32x32x16_bf16(ahi[ks], bl8, acc, 0, 0, 0);
      acc = __builtin_amdgcn_mfma_f32_32x32x16_bf16(ahi[ks], bh8, acc, 0, 0, 0);
    }
#pragma unroll
    for (int i = 0; i < 16; ++i) psum[i] += EXP2F(acc[i] * LOG2E);
  }

#pragma unroll
  for (int off = 1; off < 32; off <<= 1) {
#pragma unroll
    for (int i = 0; i < 16; ++i) psum[i] += __shfl_xor(psum[i], off, 64);
  }
  if ((lane & 31) == 0) {
    const int rbase = rg * 32 + 4 * (lane >> 5);
#pragma unroll
    for (int i = 0; i < 16; ++i)
      atomicAdd(&rsum_s[rbase + (i & 3) + 8 * (i >> 2)], psum[i]);
  }
  __syncthreads();
  if (tid < QB) rsum_s[tid] = 1.0f / rsum_s[tid];
  __syncthreads();

  floatx4 rvec[4];
  {
    const int rb = rg * 32 + 4 * (lane >> 5);
#pragma unroll
    for (int m = 0; m < 4; ++m) rvec[m] = *(const floatx4*)&rsum_s[rb + 8 * m];
  }

  // ---------- pass 2: attn + PV ----------
  f32x16 oacc = {};
  const int boff = (lane >> 5) * 8;
  const int rbase = rg * 32 + 4 * (lane >> 5);
  const int colb = cg * 32 + (lane & 31);

  for (int ch = 0; ch < NCHUNK; ++ch) {
    const size_t off = (size_t)(ch * 4 + cg) * 2048 + (size_t)lane * 8;
    f32x16 acc = {};
#pragma unroll
    for (int ks = 0; ks < 4; ++ks) {
      short8 bh8 = __builtin_bit_cast(short8, *(const ushort8v*)(KHb + off + ks * 512));
      short8 bl8 = __builtin_bit_cast(short8, *(const ushort8v*)(KLb + off + ks * 512));
      acc = __builtin_amdgcn_mfma_f32_32x32x16_bf16(alo[ks], bh8, acc, 0, 0, 0);
      acc = __builtin_amdgcn_mfma_f32_32x32x16_bf16(ahi[ks], bl8, acc, 0, 0, 0);
      acc = __builtin_amdgcn_mfma_f32_32x32x16_bf16(ahi[ks], bh8, acc, 0, 0, 0);
    }
    // exp -> normalize (in place) -> fp16 stash into Pst[ch&1]
    unsigned short* PB = &Pst[ch & 1][0];
#pragma unroll
    for (int i = 0; i < 16; ++i) {
      acc[i] = EXP2F(acc[i] * LOG2E) * rvec[i >> 2][i & 3];
      PB[(rbase + (i & 3) + 8 * (i >> 2)) * PPAD + colb] = f2h(acc[i]);
    }
    __syncthreads();
    // attn nt-stores AFTER the barrier: they drain under PV + next-chunk QK
    {
      const int colg = ch * KB + colb;
#pragma unroll
      for (int i = 0; i < 16; ++i) {
        const int rl = rbase + (i & 3) + 8 * (i >> 2);
        __builtin_nontemporal_store(acc[i], &attn_base[(size_t)rl * S_LEN + colg]);
      }
    }
    // PV: P from Pst[ch&1], V frags coalesced from ws
#pragma unroll
    for (int ks = 0; ks < 4; ++ks) {
      const int kofs = kh * 64 + ks * 16 + boff;
      ushort8v pu = *(const ushort8v*)&PB[(rg * 32 + (lane & 31)) * PPAD + kofs];
      ushort8v vu = *(const ushort8v*)(VTb + (size_t)ch * 8192 +
                                       ((size_t)((kh * 2 + dg) * 4 + ks) * 64 + lane) * 8);
      oacc = __builtin_amdgcn_mfma_f32_32x32x16_f16(
          __builtin_bit_cast(half8, pu), __builtin_bit_cast(half8, vu), oacc, 0, 0, 0);
    }
    // no second barrier: Pst is double-buffered; chunk ch+2's writes to this
    // buffer are fenced by chunk ch+1's barrier.
  }

  // combine kk-halves via LDS (alias Pst[0]: 16 KiB needed, 17 KiB there)
  float* red = (float*)&Pst[0][0];
  const int t4 = wid & 3;
  if (kh == 1) {
#pragma unroll
    for (int i = 0; i < 16; ++i) red[t4 * 1024 + i * 64 + lane] = oacc[i];
  }
  __syncthreads();
  if (kh == 0) {
#pragma unroll
    for (int i = 0; i < 16; ++i) oacc[i] += red[t4 * 1024 + i * 64 + lane];
#pragma unroll
    for (int i = 0; i < 16; ++i) {
      const int rl = rbase + (i & 3) + 8 * (i >> 2);
      out_base[(size_t)rl * D_HEAD + dg * 32 + (lane & 31)] = oacc[i];
    }
  }
}

// ================= fallback (round-3) kernels =================
__global__ __launch_bounds__(512, 4) void k_rowsum(
    const float* __restrict__ q, const float* __restrict__ k,
    float* __restrict__ outbuf) {
  __shared__ __align__(16) unsigned short KhiS[KB * KPAD];
  __shared__ __align__(16) unsigned short KloS[KB * KPAD];
  __shared__ float rsum_s[QB];
  const int tid = threadIdx.x;
  const int lane = tid & 63;
  const int wid = tid >> 6;
  const int rg = wid & 1, cg = wid >> 1;
  const int bh = blockIdx.x >> 5;
  const int qt = blockIdx.x & 31;
  const float* Q = q + (size_t)bh * S_LEN * D_HEAD;
  const float* K = k + (size_t)bh * S_LEN * D_HEAD;
  float* rinv_out = outbuf + ATTN_ELEMS + (size_t)bh * S_LEN * D_HEAD +
                    (size_t)qt * QB * D_HEAD;
  if (tid < QB) rsum_s[tid] = 0.0f;
  const int arow = qt * QB + rg * 32 + (lane & 31);
  const float* qp = Q + (size_t)arow * D_HEAD + ((lane >> 5) * 8);
  short8 ahi[4], alo[4];
#pragma unroll
  for (int ks = 0; ks < 4; ++ks) {
    floatx4 x0 = *(const floatx4*)(qp + ks * 16);
    floatx4 x1 = *(const floatx4*)(qp + ks * 16 + 4);
    ushort8v uh, ul;
#pragma unroll
    for (int j = 0; j < 4; ++j) {
      float xa = x0[j] * 0.125f; unsigned short ha = f2bf(xa);
      uh[j] = ha; ul[j] = f2bf(xa - bf2f(ha));
      float xb = x1[j] * 0.125f; unsigned short hb = f2bf(xb);
      uh[4 + j] = hb; ul[4 + j] = f2bf(xb - bf2f(hb));
    }
    ahi[ks] = __builtin_bit_cast(short8, uh);
    alo[ks] = __builtin_bit_cast(short8, ul);
  }
  float psum[16];
#pragma unroll
  for (int i = 0; i < 16; ++i) psum[i] = 0.0f;
  const int srow = tid >> 2;
  const int scol = (tid & 3) * 16;
  const int bcol = cg * 32 + (lane & 31);
  const int boff = (lane >> 5) * 8;
  for (int ch = 0; ch < NCHUNK; ++ch) {
    const int kk0 = ch * KB;
    {
      const float* src = K + (size_t)(kk0 + srow) * D_HEAD + scol;
      floatx4 v0 = *(const floatx4*)(src);
      floatx4 v1 = *(const floatx4*)(src + 4);
      floatx4 v2 = *(const floatx4*)(src + 8);
      floatx4 v3 = *(const floatx4*)(src + 12);
      ushort8v h0, h1, l0, l1;
#pragma unroll
      for (int j = 0; j < 4; ++j) {
        unsigned short a0 = f2bf(v0[j]); h0[j] = a0; l0[j] = f2bf(v0[j] - bf2f(a0));
        unsigned short a1 = f2bf(v1[j]); h0[4+j] = a1; l0[4+j] = f2bf(v1[j] - bf2f(a1));
        unsigned short a2 = f2bf(v2[j]); h1[j] = a2; l1[j] = f2bf(v2[j] - bf2f(a2));
        unsigned short a3 = f2bf(v3[j]); h1[4+j] = a3; l1[4+j] = f2bf(v3[j] - bf2f(a3));
      }
      *(ushort8v*)&KhiS[srow * KPAD + scol] = h0;
      *(ushort8v*)&KhiS[srow * KPAD + scol + 8] = h1;
      *(ushort8v*)&KloS[srow * KPAD + scol] = l0;
      *(ushort8v*)&KloS[srow * KPAD + scol + 8] = l1;
    }
    __syncthreads();
    f32x16 acc = {};
#pragma unroll
    for (int ks = 0; ks < 4; ++ks) {
      ushort8v bhu = *(const ushort8v*)&KhiS[bcol * KPAD + ks * 16 + boff];
      ushort8v blu = *(const ushort8v*)&KloS[bcol * KPAD + ks * 16 + boff];
      short8 bh8 = __builtin_bit_cast(short8, bhu);
      short8 bl8 = __builtin_bit_cast(short8, blu);
      acc = __builtin_amdgcn_mfma_f32_32x32x16_bf16(alo[ks], bh8, acc, 0, 0, 0);
      acc = __builtin_amdgcn_mfma_f32_32x32x16_bf16(ahi[ks], bl8, acc, 0, 0, 0);
      acc = __builtin_amdgcn_mfma_f32_32x32x16_bf16(ahi[ks], bh8, acc, 0, 0, 0);
    }
#pragma unroll
    for (int i = 0; i < 16; ++i) psum[i] += EXP2F(acc[i] * LOG2E);
    __syncthreads();
  }
#pragma unroll
  for (int off = 1; off < 32; off <<= 1) {
#pragma unroll
    for (int i = 0; i < 16; ++i) psum[i] += __shfl_xor(psum[i], off, 64);
  }
  if ((lane & 31) == 0) {
    const int rbase = rg * 32 + 4 * (lane >> 5);
#pragma unroll
    for (int i = 0; i < 16; ++i)
      atomicAdd(&rsum_s[rbase + (i & 3) + 8 * (i >> 2)], psum[i]);
  }
  __syncthreads();
  if (tid < QB) rinv_out[tid] = 1.0f / rsum_s[tid];
}

__global__ __launch_bounds__(512, 4) void k_attn(
    const float* __restrict__ q, const float* __restrict__ k,
    const float* __restrict__ v, float* __restrict__ outbuf) {
  __shared__ __align__(16) unsigned short KhiS[KB * KPAD];
  __shared__ __align__(16) unsigned short KloS[KB * KPAD];
  __shared__ __align__(16) unsigned short Pst[QB * PPAD];
  __shared__ __align__(16) unsigned short VtS[D_HEAD * PPAD];
  __shared__ float rinv_s[QB];
  const int tid = threadIdx.x;
  const int lane = tid & 63;
  const int wid = tid >> 6;
  const int rg = wid & 1, cg = wid >> 1;
  const int dg = (wid >> 1) & 1, kh = wid >> 2;
  const int bh = blockIdx.x >> 5;
  const int qt = blockIdx.x & 31;
  const float* Q = q + (size_t)bh * S_LEN * D_HEAD;
  const float* K = k + (size_t)bh * S_LEN * D_HEAD;
  const float* V = v + (size_t)bh * S_LEN * D_HEAD;
  float* attn_base = outbuf + (size_t)bh * S_LEN * S_LEN + (size_t)qt * QB * S_LEN;
  float* out_base = outbuf + ATTN_ELEMS + (size_t)bh * S_LEN * D_HEAD +
                    (size_t)qt * QB * D_HEAD;
  if (tid < QB) rinv_s[tid] = out_base[tid];
  const int arow = qt * QB + rg * 32 + (lane & 31);
  const float* qp = Q + (size_t)arow * D_HEAD + ((lane >> 5) * 8);
  short8 ahi[4], alo[4];
#pragma unroll
  for (int ks = 0; ks < 4; ++ks) {
    floatx4 x0 = *(const floatx4*)(qp + ks * 16);
    floatx4 x1 = *(const floatx4*)(qp + ks * 16 + 4);
    ushort8v uh, ul;
#pragma unroll
    for (int j = 0; j < 4; ++j) {
      float xa = x0[j] * 0.125f; unsigned short ha = f2bf(xa);
      uh[j] = ha; ul[j] = f2bf(xa - bf2f(ha));
      float xb = x1[j] * 0.125f; unsigned short hb = f2bf(xb);
      uh[4 + j] = hb; ul[4 + j] = f2bf(xb - bf2f(hb));
    }
    ahi[ks] = __builtin_bit_cast(short8, uh);
    alo[ks] = __builtin_bit_cast(short8, ul);
  }
  __syncthreads();
  floatx4 rvec[4];
  {
    const int rb = rg * 32 + 4 * (lane >> 5);
#pragma unroll
    for (int m = 0; m < 4; ++m) rvec[m] = *(const floatx4*)&rinv_s[rb + 8 * m];
  }
  f32x16 oacc = {};
  const int srow = tid >> 2;
  const int scol = (tid & 3) * 16;
  const int bcol = cg * 32 + (lane & 31);
  const int boff = (lane >> 5) * 8;
  for (int ch = 0; ch < NCHUNK; ++ch) {
    const int kk0 = ch * KB;
    {
      const float* src = K + (size_t)(kk0 + srow) * D_HEAD + scol;
      floatx4 v0 = *(const floatx4*)(src);
      floatx4 v1 = *(const floatx4*)(src + 4);
      floatx4 v2 = *(const floatx4*)(src + 8);
      floatx4 v3 = *(const floatx4*)(src + 12);
      ushort8v h0, h1, l0, l1;
#pragma unroll
      for (int j = 0; j < 4; ++j) {
        unsigned short a0 = f2bf(v0[j]); h0[j] = a0; l0[j] = f2bf(v0[j] - bf2f(a0));
        unsigned short a1 = f2bf(v1[j]); h0[4+j] = a1; l0[4+j] = f2bf(v1[j] - bf2f(a1));
        unsigned short a2 = f2bf(v2[j]); h1[j] = a2; l1[j] = f2bf(v2[j] - bf2f(a2));
        unsigned short a3 = f2bf(v3[j]); h1[4+j] = a3; l1[4+j] = f2bf(v3[j] - bf2f(a3));
      }
      *(ushort8v*)&KhiS[srow * KPAD + scol] = h0;
      *(ushort8v*)&KhiS[srow * KPAD + scol + 8] = h1;
      *(ushort8v*)&KloS[srow * KPAD + scol] = l0;
      *(ushort8v*)&KloS[srow * KPAD + scol + 8] = l1;
    }
    {
#pragma unroll
      for (int half = 0; half < 2; ++half) {
        const float* vsrc = V + (size_t)(kk0 + half * 64 + wid * 8) * D_HEAD + lane;
        ushort8v hv;
#pragma unroll
        for (int i = 0; i < 8; ++i) hv[i] = f2h(vsrc[(size_t)i * D_HEAD]);
        *(ushort8v*)&VtS[lane * PPAD + half * 64 + wid * 8] = hv;
      }
    }
    __syncthreads();
    f32x16 acc = {};
#pragma unroll
    for (int ks = 0; ks < 4; ++ks) {
      ushort8v bhu = *(const ushort8v*)&KhiS[bcol * KPAD + ks * 16 + boff];
      ushort8v blu = *(const ushort8v*)&KloS[bcol * KPAD + ks * 16 + boff];
      short8 bh8 = __builtin_bit_cast(short8, bhu);
      short8 bl8 = __builtin_bit_cast(short8, blu);
      acc = __builtin_amdgcn_mfma_f32_32x32x16_bf16(alo[ks], bh8, acc, 0, 0, 0);
      acc = __builtin_amdgcn_mfma_f32_32x32x16_bf16(ahi[ks], bl8, acc, 0, 0, 0);
      acc = __builtin_amdgcn_mfma_f32_32x32x16_bf16(ahi[ks], bh8, acc, 0, 0, 0);
    }
    {
      const int rbase = rg * 32 + 4 * (lane >> 5);
      const int colg = kk0 + cg * 32 + (lane & 31);
#pragma unroll
      for (int i = 0; i < 16; ++i) {
        float p = EXP2F(acc[i] * LOG2E);
        float at = p * rvec[i >> 2][i & 3];
        const int rl = rbase + (i & 3) + 8 * (i >> 2);
        __builtin_nontemporal_store(at, &attn_base[(size_t)rl * S_LEN + colg]);
        Pst[rl * PPAD + cg * 32 + (lane & 31)] = f2h(at);
      }
    }
    __syncthreads();
#pragma unroll
    for (int ks = 0; ks < 4; ++ks) {
      const int kofs = kh * 64 + ks * 16 + boff;
      ushort8v pu = *(const ushort8v*)&Pst[(rg * 32 + (lane & 31)) * PPAD + kofs];
      ushort8v vu = *(const ushort8v*)&VtS[(dg * 32 + (lane & 31)) * PPAD + kofs];
      oacc = __builtin_amdgcn_mfma_f32_32x32x16_f16(
          __builtin_bit_cast(half8, pu), __builtin_bit_cast(half8, vu), oacc, 0, 0, 0);
    }
    __syncthreads();
  }
  float* red = (float*)KhiS;
  const int t4 = wid & 3;
  if (kh == 1) {
#pragma unroll
    for (int i = 0; i < 16; ++i) red[t4 * 1024 + i * 64 + lane] = oacc[i];
  }
  __syncthreads();
  if (kh == 0) {
#pragma unroll
    for (int i = 0; i < 16; ++i) oacc[i] += red[t4 * 1024 + i * 64 + lane];
    const int rbase = rg * 32 + 4 * (lane >> 5);
#pragma unroll
    for (int i = 0; i < 16; ++i) {
      const int rl = rbase + (i & 3) + 8 * (i >> 2);
      out_base[(size_t)rl * D_HEAD + dg * 32 + (lane & 31)] = oacc[i];
    }
  }
}

extern "C" void kernel_launch(void* const* d_in, const int* in_sizes, int n_in,
                              void* d_out, int out_size, void* d_ws, size_t ws_size,
                              hipStream_t stream) {
  const float* q = (const float*)d_in[0];
  const float* k = (const float*)d_in[1];
  const float* v = (const float*)d_in[2];
  float* out = (float*)d_out;
  (void)in_sizes; (void)n_in; (void)out_size;

  dim3 blk(512);
  if (ws_size >= WS_NEEDED_BYTES) {
    unsigned short* wsu = (unsigned short*)d_ws;
    unsigned short* khi = wsu + WSE_KHI;
    unsigned short* klo = wsu + WSE_KLO;
    unsigned short* vt = wsu + WSE_VT;
    hipLaunchKernelGGL(k_prep, dim3(1024), blk, 0, stream, k, v, khi, klo, vt);
    hipLaunchKernelGGL(k_fused, dim3(1024), blk, 0, stream, q, khi, klo, vt, out);
  } else {
    hipLaunchKernelGGL(k_rowsum, dim3(1024), blk, 0, stream, q, k, out);
    hipLaunchKernelGGL(k_attn, dim3(1024), blk, 0, stream, q, k, v, out);
  }
}